// Round 5
// baseline (2593.597 us; speedup 1.0000x reference)
//
#include <hip/hip_runtime.h>
#include <math.h>

#define BATCH 8
#define WID   32
#define NX    64
#define NY    64
#define NT    40
#define M1C   12
#define KT    8      // M3
#define KXC   24
#define KYC   24
#define NXY   (NX*NY)        // 4096
#define NXYT  (NXY*NT)       // 163840
#define NP    (BATCH*NXYT)   // 1310720

#define TWO_PI 6.283185307179586f

static __device__ __forceinline__ float gelu_f(float v){
  return 0.5f*v*(1.0f + erff(v*0.7071067811865476f));
}

// barrier that does NOT drain vmcnt (keeps global prefetch loads in flight).
static __device__ __forceinline__ void barrier_lds(){
  asm volatile("s_waitcnt lgkmcnt(0)\n\ts_barrier" ::: "memory");
}

// V layout throughout: [b][x][y][t][c]  (channel-innermost, plane = 1280 floats)

// ---------------- fc0: [B,X,Y,T,5] -> V ----------------
__global__ __launch_bounds__(256) void k_fc0(const float* __restrict__ h, const float* __restrict__ x,
                                             const float* __restrict__ w, const float* __restrict__ b,
                                             float* __restrict__ V){
  __shared__ float sw[160], sb[32];
  int tid=threadIdx.x;
  if(tid<160) sw[tid]=w[tid];
  if(tid<32)  sb[tid]=b[tid];
  __syncthreads();
  int pl = tid>>3, q = tid&7;
  int p = blockIdx.x*32 + pl;
  float i0=h[(size_t)p*2], i1=h[(size_t)p*2+1];
  float i2=x[(size_t)p*3], i3=x[(size_t)p*3+1], i4=x[(size_t)p*3+2];
  int c0=q*4;
  float4 o;
  float* po=(float*)&o;
  #pragma unroll
  for(int u=0;u<4;u++){
    int c=c0+u;
    po[u] = sb[c] + i0*sw[c] + i1*sw[32+c] + i2*sw[64+c] + i3*sw[96+c] + i4*sw[128+c];
  }
  ((float4*)V)[(size_t)p*8 + q] = o;
}

// ------- fused forward T+Y per (b,x): V slice -> F2 [bc*64+x][ky*8+kt] -------
__global__ __launch_bounds__(256) void k_fwd_ty(const float* __restrict__ V, float2* __restrict__ F2){
  __shared__ __align__(16) unsigned char smem[64256];
  float*  vt    = (float*)smem;                 // 10240 floats (one 8-y group)
  float2* f2out = (float2*)smem;                // alias (after last compute): 32*193
  float2* twt   = (float2*)(smem + 49408);      // 8*40
  float2* twy   = (float2*)(smem + 51968);      // 24*64
  int tid = threadIdx.x;
  int b = blockIdx.x >> 6, x = blockIdx.x & 63;
  int c = tid & 31, k = tid >> 5;
  for(int i=tid;i<KT*NT;i+=256){
    int kk=i/NT, t=i-kk*NT;
    float ang = -TWO_PI*(float)((kk*t)%NT)/(float)NT;
    twt[i] = make_float2(cosf(ang), sinf(ang));
  }
  for(int i=tid;i<KYC*NY;i+=256){
    int ky=i/NY, y=i-ky*NY;
    int f = ky<M1C ? ky : ky+40;
    float ang = -TWO_PI*(float)((f*y)%NY)/(float)NY;
    twy[i] = make_float2(cosf(ang), sinf(ang));
  }
  float2 acc[KYC];
  #pragma unroll
  for(int ky=0;ky<KYC;ky++) acc[ky]=make_float2(0.f,0.f);
  const float4* src = (const float4*)(V + (size_t)(b*NX+x)*(NY*NT*WID));
  for(int g=0; g<8; g++){
    __syncthreads();                       // prev compute / table init done
    #pragma unroll
    for(int r=0;r<10;r++) ((float4*)vt)[r*256+tid] = src[g*2560 + r*256 + tid];
    __syncthreads();
    for(int yl=0; yl<8; yl++){
      float sr=0.f, si=0.f;
      const float* vp = vt + yl*1280 + c;
      const float2* tw = twt + k*NT;
      #pragma unroll 8
      for(int t=0;t<NT;t++){
        float v = vp[t*32];                // lanes 0-31 contiguous; 32-63 broadcast
        float2 w = tw[t];
        sr += v*w.x; si += v*w.y;
      }
      int y = g*8 + yl;
      #pragma unroll
      for(int ky=0;ky<KYC;ky++){
        float2 wy = twy[ky*NY + y];
        acc[ky].x += sr*wy.x - si*wy.y;
        acc[ky].y += sr*wy.y + si*wy.x;
      }
    }
  }
  __syncthreads();                         // vt dead -> f2out alias safe
  #pragma unroll
  for(int ky=0;ky<KYC;ky++) f2out[c*193 + ky*KT + k] = acc[ky];
  __syncthreads();
  for(int i=tid;i<WID*KYC*KT;i+=256){
    int cc=i/192, e=i-cc*192;
    F2[((size_t)(b*WID+cc)*NX + x)*(KYC*KT) + e] = f2out[cc*193 + e];
  }
}

// ---------------- forward X: F2 -> F3 [B,32,24,24,8] cplx ----------------
__global__ __launch_bounds__(256) void k_fwd_x(const float2* __restrict__ F2, float2* __restrict__ F3){
  __shared__ float2 tile[NX*KT];
  __shared__ float twc[KXC*65], tws[KXC*65];
  int tid=threadIdx.x;
  int bc = blockIdx.x / KYC;
  int ky = blockIdx.x - bc*KYC;
  for(int i=tid;i<NX*KT;i+=256){
    int xx=i/KT, kt=i-xx*KT;
    tile[i] = F2[((size_t)bc*NX + xx)*(KYC*KT) + ky*KT + kt];
  }
  for(int i=tid;i<KXC*NX;i+=256){
    int kx=i/NX, xx=i-kx*NX;
    int f = kx<M1C ? kx : kx+40;
    float ang = -TWO_PI*(float)((f*xx)%NX)/(float)NX;
    twc[kx*65+xx]=cosf(ang); tws[kx*65+xx]=sinf(ang);
  }
  __syncthreads();
  for(int item=tid; item<KXC*KT; item+=256){
    int kx=item/KT, kt=item-kx*KT;
    float sr=0.f, si=0.f;
    #pragma unroll 8
    for(int xx=0;xx<NX;xx++){
      float2 a = tile[xx*KT+kt];
      float c = twc[kx*65+xx], s = tws[kx*65+xx];
      sr += a.x*c - a.y*s;
      si += a.x*s + a.y*c;
    }
    F3[(size_t)bc*(KXC*KYC*KT) + kx*(KYC*KT) + ky*KT + kt] = make_float2(sr,si);
  }
}

// ---------------- channel mix: F3 -> F4 ----------------
__global__ __launch_bounds__(256) void k_mix(const float2* __restrict__ F3, const float* __restrict__ wr,
                                             const float* __restrict__ wi, float2* __restrict__ F4){
  int idx = blockIdx.x*256 + threadIdx.x;
  int b = idx / (WID*4608);
  int r = idx - b*(WID*4608);
  int o = r / 4608;
  int mode = r - o*4608;
  int kx = mode/192;
  int ky = (mode/KT)%KYC;
  int xp = (kx>=M1C), yp = (ky>=M1C);
  int m1 = kx - M1C*xp, m2 = ky - M1C*yp;
  int blk = xp + 2*yp;
  int kt = mode & 7;
  size_t widx = (size_t)blk*1179648 + (size_t)o*1152 + m1*96 + m2*8 + kt;
  const float2* src = F3 + (size_t)b*WID*4608 + mode;
  float ar=0.f, ai=0.f;
  #pragma unroll 8
  for(int i=0;i<WID;i++){
    float2 a = src[(size_t)i*4608];
    float r_ = wr[widx], q_ = wi[widx];
    ar += a.x*r_ - a.y*q_;
    ai += a.x*q_ + a.y*r_;
    widx += 36864;
  }
  F4[((size_t)b*WID + o)*4608 + mode] = make_float2(ar, ai);
}

// ---------------- inverse X: F4 -> F2 (1/64 folded) ----------------
__global__ __launch_bounds__(256) void k_inv_x(const float2* __restrict__ F4, float2* __restrict__ F2){
  __shared__ float2 tile[KXC*KT];
  __shared__ float twc[NX*KXC], tws[NX*KXC];
  int tid=threadIdx.x;
  int bc = blockIdx.x / KYC, ky = blockIdx.x - (blockIdx.x/KYC)*KYC;
  for(int i=tid;i<KXC*KT;i+=256){
    int kx=i/KT, kt=i-kx*KT;
    tile[i] = F4[(size_t)bc*4608 + kx*(KYC*KT) + ky*KT + kt];
  }
  for(int i=tid;i<NX*KXC;i+=256){
    int xx=i/KXC, kx=i-xx*KXC;
    int f = kx<M1C ? kx : kx+40;
    float ang = TWO_PI*(float)((f*xx)%NX)/(float)NX;
    twc[i]=cosf(ang)*(1.0f/64.0f); tws[i]=sinf(ang)*(1.0f/64.0f);
  }
  __syncthreads();
  for(int item=tid; item<NX*KT; item+=256){
    int xx=item/KT, kt=item-xx*KT;
    float sr=0.f, si=0.f;
    #pragma unroll 8
    for(int kx=0;kx<KXC;kx++){
      float2 a = tile[kx*KT+kt];
      float c = twc[xx*KXC+kx], s = tws[xx*KXC+kx];
      sr += a.x*c - a.y*s;
      si += a.x*s + a.y*c;
    }
    F2[((size_t)bc*NX + xx)*(KYC*KT) + ky*KT + kt] = make_float2(sr,si);
  }
}

// ------- fused inv-Y + irfft-T + conv1x1 [+gelu], in-place on V -------
// grid = B*NX*2, block = (b, x, y-half). With c-innermost V the per-y tile
// [t][c] is 1280 contiguous floats: linear loads, full-line stores.
template<bool GELU>
__global__ __launch_bounds__(256,4) void k_conv(const float2* __restrict__ F2, const float* __restrict__ wcv,
                                                const float* __restrict__ bcv, float* __restrict__ V){
  __shared__ __align__(16) unsigned char smem[24576];
  float*  vt0  = (float*)smem;                  // 5120 B
  float*  vt1  = (float*)(smem+5120);           // 5120 B
  float2* ftc  = (float2*)(smem+10240);         // 2048 B
  float2* tcts = (float2*)(smem+12288);         // 2560 B
  float2* twy  = (float2*)(smem+14848);         // 6144 B (end 20992)
  float2* f2h  = (float2*)smem;                 // prologue alias: 24576 B

  int tid=threadIdx.x;
  int b  = blockIdx.x >> 7;
  int x  = (blockIdx.x >> 1) & 63;
  int y0 = (blockIdx.x & 1) * 32;
  int cid = tid & 31, ktid = tid >> 5;   // inv-Y identity
  int oid = tid & 31, tg  = tid >> 5;    // conv identity; t = tg*5+j

  // ---- prologue: F2 slice -> registers via LDS (two halves) ----
  float2 fr[KYC];
  #pragma unroll
  for(int half=0; half<2; half++){
    for(int i=tid;i<1536;i+=256){
      int cc=i/96, q=i-cc*96;
      ((float4*)f2h)[i] = *((const float4*)(F2 + ((size_t)(b*WID + half*16 + cc)*NX + x)*(KYC*KT)) + q);
    }
    __syncthreads();
    if((cid>>4) == half){
      const float2* fp = f2h + (cid&15)*192 + ktid;
      #pragma unroll
      for(int ky=0;ky<KYC;ky++) fr[ky] = fp[ky*8];
    }
    __syncthreads();
  }
  float wreg[WID];
  #pragma unroll
  for(int cc=0;cc<WID;cc++) wreg[cc] = wcv[oid*WID + cc];
  float breg = bcv[oid];
  for(int i=tid;i<KT*NT;i+=256){
    int k=i/NT, t=i-k*NT;
    float ang = TWO_PI*(float)((k*t)%NT)/(float)NT;
    float sc = (k==0 ? 1.0f : 2.0f)*(1.0f/(float)NT);
    tcts[i] = make_float2(cosf(ang)*sc, sinf(ang)*sc);
  }
  for(int i=tid;i<32*KYC;i+=256){
    int yy=i/KYC, ky=i-yy*KYC;
    int f = ky<M1C ? ky : ky+40;
    float ang = TWO_PI*(float)((f*(y0+yy))%NY)/(float)NY;
    twy[i] = make_float2(cosf(ang)*(1.0f/64.0f), sinf(ang)*(1.0f/64.0f));
  }
  float* plane = V + (size_t)((b*NX+x)*NY + y0)*(NT*WID);
  const float4* gp = (const float4*)plane;
  bool has2 = tid < 64;
  // prologue fill of vt0 (y=0): linear chunks
  float4 g0 = gp[tid];
  float4 g1 = has2 ? gp[256+tid] : make_float4(0,0,0,0);
  ((float4*)vt0)[tid] = g0;
  if(has2) ((float4*)vt0)[256+tid] = g1;
  __syncthreads();

  for(int y=0;y<32;y++){
    if(y+1 < 32){                         // prefetch next plane (in flight across barrier)
      g0 = gp[(size_t)(y+1)*320 + tid];
      if(has2) g1 = gp[(size_t)(y+1)*320 + 256 + tid];
    }
    { // inverse-Y in registers -> ftc[kt][c]
      const float2* tw = twy + y*KYC;
      float sr=0.f, si=0.f;
      #pragma unroll
      for(int ky=0;ky<KYC;ky++){
        float2 w = tw[ky];
        float2 a = fr[ky];
        sr += a.x*w.x - a.y*w.y;
        si += a.x*w.y + a.y*w.x;
      }
      ftc[ktid*32 + cid] = make_float2(sr,si);
    }
    barrier_lds();
    { // conv1x1 + irfft-T; direct full-line stores
      float2 fR[KT];
      #pragma unroll
      for(int k=0;k<KT;k++) fR[k] = ftc[k*32 + oid];
      const float* vb = (y&1) ? vt1 : vt0;
      float* outp = plane + (size_t)y*(NT*WID);
      #pragma unroll
      for(int j=0;j<5;j++){
        int t = tg*5 + j;
        float a = breg;
        const float* vrow = vb + t*32;
        #pragma unroll
        for(int c4=0;c4<WID;c4+=4){
          float4 vv = *(const float4*)(vrow + c4);   // broadcast b128
          a += vv.x*wreg[c4] + vv.y*wreg[c4+1] + vv.z*wreg[c4+2] + vv.w*wreg[c4+3];
        }
        #pragma unroll
        for(int k=0;k<KT;k++){
          float2 w = tcts[k*NT + t];
          a += fR[k].x*w.x - fR[k].y*w.y;
        }
        outp[t*32 + oid] = GELU ? gelu_f(a) : a;     // lanes 0-31: one full 128B line
      }
    }
    if(y+1 < 32){
      float* d = (y&1) ? vt0 : vt1;
      ((float4*)d)[tid] = g0;
      if(has2) ((float4*)d)[256+tid] = g1;
    }
    barrier_lds();
  }
}

// ---------------- fused fc1+gelu+fc2: V -> out [B,X,Y,T,2] ----------------
__global__ __launch_bounds__(256) void k_mlp(const float* __restrict__ V, const float* __restrict__ w1,
                                             const float* __restrict__ b1, const float* __restrict__ w2,
                                             const float* __restrict__ b2, float* __restrict__ out){
  __shared__ float sw1[WID*64];
  __shared__ float sb1[64], sw2[128], sb2[2];
  int tid=threadIdx.x;
  for(int i=tid;i<WID*64;i+=256) sw1[i]=w1[i];
  if(tid<64) sb1[tid]=b1[tid];
  if(tid<128) sw2[tid]=w2[tid];
  if(tid<2) sb2[tid]=b2[tid];
  __syncthreads();
  int p = blockIdx.x*256 + tid;
  float vcol[WID];
  const float4* vp = (const float4*)(V + (size_t)p*WID);
  #pragma unroll
  for(int q=0;q<8;q++){
    float4 vv = vp[q];
    vcol[4*q]=vv.x; vcol[4*q+1]=vv.y; vcol[4*q+2]=vv.z; vcol[4*q+3]=vv.w;
  }
  float o0=sb2[0], o1=sb2[1];
  #pragma unroll 2
  for(int j=0;j<64;j++){
    float a=sb1[j];
    #pragma unroll
    for(int cc=0;cc<WID;cc++) a += vcol[cc]*sw1[cc*64+j];
    a = gelu_f(a);
    o0 += a*sw2[2*j]; o1 += a*sw2[2*j+1];
  }
  ((float2*)out)[p]=make_float2(o0,o1);
}

extern "C" void kernel_launch(void* const* d_in, const int* in_sizes, int n_in,
                              void* d_out, int out_size, void* d_ws, size_t ws_size,
                              hipStream_t stream){
  const float* h     = (const float*)d_in[0];
  const float* x     = (const float*)d_in[1];
  const float* fc0_w = (const float*)d_in[2];
  const float* fc0_b = (const float*)d_in[3];
  const float* scwr[3] = {(const float*)d_in[4], (const float*)d_in[6], (const float*)d_in[8]};
  const float* scwi[3] = {(const float*)d_in[5], (const float*)d_in[7], (const float*)d_in[9]};
  const float* cw[3]   = {(const float*)d_in[10], (const float*)d_in[12], (const float*)d_in[14]};
  const float* cb[3]   = {(const float*)d_in[11], (const float*)d_in[13], (const float*)d_in[15]};
  const float* fc1_w = (const float*)d_in[16];
  const float* fc1_b = (const float*)d_in[17];
  const float* fc2_w = (const float*)d_in[18];
  const float* fc2_b = (const float*)d_in[19];

  // workspace: V (167.8 MB, layout [b,x,y,t,c]) | F2 (25.2 MB) | F4 (9.4 MB)
  // F3 lives in d_out (9.4 MB <= 10.5 MB) until k_mlp overwrites it.
  const size_t VSZ = (size_t)BATCH*WID*NXYT;
  float*  V  = (float*)d_ws;
  float2* F2 = (float2*)(V + VSZ);
  float2* F4 = F2 + (size_t)BATCH*WID*NX*KYC*KT;
  float2* F3 = (float2*)d_out;

  k_fc0<<<NP/32, 256, 0, stream>>>(h, x, fc0_w, fc0_b, V);
  for(int L=0; L<3; L++){
    k_fwd_ty<<<BATCH*NX, 256, 0, stream>>>(V, F2);
    k_fwd_x<<<(BATCH*WID)*KYC, 256, 0, stream>>>(F2, F3);
    k_mix<<<(BATCH*WID*KXC*KYC*KT)/256, 256, 0, stream>>>(F3, scwr[L], scwi[L], F4);
    k_inv_x<<<(BATCH*WID)*KYC, 256, 0, stream>>>(F4, F2);
    if(L<2) k_conv<true ><<<BATCH*NX*2, 256, 0, stream>>>(F2, cw[L], cb[L], V);
    else    k_conv<false><<<BATCH*NX*2, 256, 0, stream>>>(F2, cw[L], cb[L], V);
  }
  k_mlp<<<NP/256, 256, 0, stream>>>(V, fc1_w, fc1_b, fc2_w, fc2_b, (float*)d_out);
}

// Round 6
// 1707.081 us; speedup vs baseline: 1.5193x; 1.5193x over previous
//
#include <hip/hip_runtime.h>
#include <math.h>

#define BATCH 8
#define WID   32
#define NX    64
#define NY    64
#define NT    40
#define M1C   12
#define KT    8      // M3
#define KXC   24
#define KYC   24
#define NXY   (NX*NY)        // 4096
#define NXYT  (NXY*NT)       // 163840
#define NP    (BATCH*NXYT)   // 1310720

#define TWO_PI 6.283185307179586f

static __device__ __forceinline__ float gelu_f(float v){
  return 0.5f*v*(1.0f + erff(v*0.7071067811865476f));
}

// barrier that does NOT drain vmcnt (keeps global prefetch loads in flight).
static __device__ __forceinline__ void barrier_lds(){
  asm volatile("s_waitcnt lgkmcnt(0)\n\ts_barrier" ::: "memory");
}

// V layout throughout: [b][x][y][t][c]  (channel-innermost, plane = 1280 floats)

// ---------------- fc0: [B,X,Y,T,5] -> V ----------------
__global__ __launch_bounds__(256) void k_fc0(const float* __restrict__ h, const float* __restrict__ x,
                                             const float* __restrict__ w, const float* __restrict__ b,
                                             float* __restrict__ V){
  __shared__ float sw[160], sb[32];
  int tid=threadIdx.x;
  if(tid<160) sw[tid]=w[tid];
  if(tid<32)  sb[tid]=b[tid];
  __syncthreads();
  int pl = tid>>3, q = tid&7;
  int p = blockIdx.x*32 + pl;
  float i0=h[(size_t)p*2], i1=h[(size_t)p*2+1];
  float i2=x[(size_t)p*3], i3=x[(size_t)p*3+1], i4=x[(size_t)p*3+2];
  int c0=q*4;
  float4 o;
  float* po=(float*)&o;
  #pragma unroll
  for(int u=0;u<4;u++){
    int c=c0+u;
    po[u] = sb[c] + i0*sw[c] + i1*sw[32+c] + i2*sw[64+c] + i3*sw[96+c] + i4*sw[128+c];
  }
  ((float4*)V)[(size_t)p*8 + q] = o;
}

// ------- fused forward T+Y per (b,x): V slice -> F2 [bc*64+x][ky*8+kt] -------
__global__ __launch_bounds__(256) void k_fwd_ty(const float* __restrict__ V, float2* __restrict__ F2){
  __shared__ __align__(16) unsigned char smem[64256];
  float*  vt    = (float*)smem;                 // 10240 floats (one 8-y group)
  float2* f2out = (float2*)smem;                // alias (after last compute): 32*193
  float2* twt   = (float2*)(smem + 49408);      // 8*40
  float2* twy   = (float2*)(smem + 51968);      // 24*64
  int tid = threadIdx.x;
  int b = blockIdx.x >> 6, x = blockIdx.x & 63;
  int c = tid & 31, k = tid >> 5;
  for(int i=tid;i<KT*NT;i+=256){
    int kk=i/NT, t=i-kk*NT;
    float ang = -TWO_PI*(float)((kk*t)%NT)/(float)NT;
    twt[i] = make_float2(cosf(ang), sinf(ang));
  }
  for(int i=tid;i<KYC*NY;i+=256){
    int ky=i/NY, y=i-ky*NY;
    int f = ky<M1C ? ky : ky+40;
    float ang = -TWO_PI*(float)((f*y)%NY)/(float)NY;
    twy[i] = make_float2(cosf(ang), sinf(ang));
  }
  float2 acc[KYC];
  #pragma unroll
  for(int ky=0;ky<KYC;ky++) acc[ky]=make_float2(0.f,0.f);
  const float4* src = (const float4*)(V + (size_t)(b*NX+x)*(NY*NT*WID));
  for(int g=0; g<8; g++){
    __syncthreads();                       // prev compute / table init done
    #pragma unroll
    for(int r=0;r<10;r++) ((float4*)vt)[r*256+tid] = src[g*2560 + r*256 + tid];
    __syncthreads();
    for(int yl=0; yl<8; yl++){
      float sr=0.f, si=0.f;
      const float* vp = vt + yl*1280 + c;
      const float2* tw = twt + k*NT;
      #pragma unroll 8
      for(int t=0;t<NT;t++){
        float v = vp[t*32];                // lanes 0-31 contiguous; 32-63 broadcast
        float2 w = tw[t];
        sr += v*w.x; si += v*w.y;
      }
      int y = g*8 + yl;
      #pragma unroll
      for(int ky=0;ky<KYC;ky++){
        float2 wy = twy[ky*NY + y];
        acc[ky].x += sr*wy.x - si*wy.y;
        acc[ky].y += sr*wy.y + si*wy.x;
      }
    }
  }
  __syncthreads();                         // vt dead -> f2out alias safe
  #pragma unroll
  for(int ky=0;ky<KYC;ky++) f2out[c*193 + ky*KT + k] = acc[ky];
  __syncthreads();
  for(int i=tid;i<WID*KYC*KT;i+=256){
    int cc=i/192, e=i-cc*192;
    F2[((size_t)(b*WID+cc)*NX + x)*(KYC*KT) + e] = f2out[cc*193 + e];
  }
}

// ---------------- forward X: F2 -> F3 [B,32,24,24,8] cplx ----------------
__global__ __launch_bounds__(256) void k_fwd_x(const float2* __restrict__ F2, float2* __restrict__ F3){
  __shared__ float2 tile[NX*KT];
  __shared__ float twc[KXC*65], tws[KXC*65];
  int tid=threadIdx.x;
  int bc = blockIdx.x / KYC;
  int ky = blockIdx.x - bc*KYC;
  for(int i=tid;i<NX*KT;i+=256){
    int xx=i/KT, kt=i-xx*KT;
    tile[i] = F2[((size_t)bc*NX + xx)*(KYC*KT) + ky*KT + kt];
  }
  for(int i=tid;i<KXC*NX;i+=256){
    int kx=i/NX, xx=i-kx*NX;
    int f = kx<M1C ? kx : kx+40;
    float ang = -TWO_PI*(float)((f*xx)%NX)/(float)NX;
    twc[kx*65+xx]=cosf(ang); tws[kx*65+xx]=sinf(ang);
  }
  __syncthreads();
  for(int item=tid; item<KXC*KT; item+=256){
    int kx=item/KT, kt=item-kx*KT;
    float sr=0.f, si=0.f;
    #pragma unroll 8
    for(int xx=0;xx<NX;xx++){
      float2 a = tile[xx*KT+kt];
      float c = twc[kx*65+xx], s = tws[kx*65+xx];
      sr += a.x*c - a.y*s;
      si += a.x*s + a.y*c;
    }
    F3[(size_t)bc*(KXC*KYC*KT) + kx*(KYC*KT) + ky*KT + kt] = make_float2(sr,si);
  }
}

// ---------------- channel mix: F3 -> F4 ----------------
__global__ __launch_bounds__(256) void k_mix(const float2* __restrict__ F3, const float* __restrict__ wr,
                                             const float* __restrict__ wi, float2* __restrict__ F4){
  int idx = blockIdx.x*256 + threadIdx.x;
  int b = idx / (WID*4608);
  int r = idx - b*(WID*4608);
  int o = r / 4608;
  int mode = r - o*4608;
  int kx = mode/192;
  int ky = (mode/KT)%KYC;
  int xp = (kx>=M1C), yp = (ky>=M1C);
  int m1 = kx - M1C*xp, m2 = ky - M1C*yp;
  int blk = xp + 2*yp;
  int kt = mode & 7;
  size_t widx = (size_t)blk*1179648 + (size_t)o*1152 + m1*96 + m2*8 + kt;
  const float2* src = F3 + (size_t)b*WID*4608 + mode;
  float ar=0.f, ai=0.f;
  #pragma unroll 8
  for(int i=0;i<WID;i++){
    float2 a = src[(size_t)i*4608];
    float r_ = wr[widx], q_ = wi[widx];
    ar += a.x*r_ - a.y*q_;
    ai += a.x*q_ + a.y*r_;
    widx += 36864;
  }
  F4[((size_t)b*WID + o)*4608 + mode] = make_float2(ar, ai);
}

// ---------------- inverse X: F4 -> F2 (1/64 folded) ----------------
__global__ __launch_bounds__(256) void k_inv_x(const float2* __restrict__ F4, float2* __restrict__ F2){
  __shared__ float2 tile[KXC*KT];
  __shared__ float twc[NX*KXC], tws[NX*KXC];
  int tid=threadIdx.x;
  int bc = blockIdx.x / KYC, ky = blockIdx.x - (blockIdx.x/KYC)*KYC;
  for(int i=tid;i<KXC*KT;i+=256){
    int kx=i/KT, kt=i-kx*KT;
    tile[i] = F4[(size_t)bc*4608 + kx*(KYC*KT) + ky*KT + kt];
  }
  for(int i=tid;i<NX*KXC;i+=256){
    int xx=i/KXC, kx=i-xx*KXC;
    int f = kx<M1C ? kx : kx+40;
    float ang = TWO_PI*(float)((f*xx)%NX)/(float)NX;
    twc[i]=cosf(ang)*(1.0f/64.0f); tws[i]=sinf(ang)*(1.0f/64.0f);
  }
  __syncthreads();
  for(int item=tid; item<NX*KT; item+=256){
    int xx=item/KT, kt=item-xx*KT;
    float sr=0.f, si=0.f;
    #pragma unroll 8
    for(int kx=0;kx<KXC;kx++){
      float2 a = tile[kx*KT+kt];
      float c = twc[xx*KXC+kx], s = tws[xx*KXC+kx];
      sr += a.x*c - a.y*s;
      si += a.x*s + a.y*c;
    }
    F2[((size_t)bc*NX + xx)*(KYC*KT) + ky*KT + kt] = make_float2(sr,si);
  }
}

// ------- fused inv-Y + irfft-T + conv1x1 [+gelu], in-place on V -------
// grid = B*NX*2, block = (b, x, y-half). NOTE: no min-waves clamp — the kernel
// needs ~130 VGPRs (fr[24]c + wreg[32] + prefetch); clamping to (256,4) forced
// VGPR=64 and spilled fr/wreg to scratch = 1.3 GB/dispatch of fetch (R3-R5 bug).
template<bool GELU>
__global__ __launch_bounds__(256) void k_conv(const float2* __restrict__ F2, const float* __restrict__ wcv,
                                              const float* __restrict__ bcv, float* __restrict__ V){
  __shared__ __align__(16) unsigned char smem[24576];
  float*  vt0  = (float*)smem;                  // 5120 B
  float*  vt1  = (float*)(smem+5120);           // 5120 B
  float2* ftc  = (float2*)(smem+10240);         // 2048 B
  float2* tcts = (float2*)(smem+12288);         // 2560 B
  float2* twy  = (float2*)(smem+14848);         // 6144 B (end 20992)
  float2* f2h  = (float2*)smem;                 // prologue alias: 24576 B

  int tid=threadIdx.x;
  int b  = blockIdx.x >> 7;
  int x  = (blockIdx.x >> 1) & 63;
  int y0 = (blockIdx.x & 1) * 32;
  int cid = tid & 31, ktid = tid >> 5;   // inv-Y identity
  int oid = tid & 31, tg  = tid >> 5;    // conv identity; t = tg*5+j

  // ---- prologue: F2 slice -> registers via LDS (two halves) ----
  float2 fr[KYC];
  #pragma unroll
  for(int half=0; half<2; half++){
    for(int i=tid;i<1536;i+=256){
      int cc=i/96, q=i-cc*96;
      ((float4*)f2h)[i] = *((const float4*)(F2 + ((size_t)(b*WID + half*16 + cc)*NX + x)*(KYC*KT)) + q);
    }
    __syncthreads();
    if((cid>>4) == half){
      const float2* fp = f2h + (cid&15)*192 + ktid;
      #pragma unroll
      for(int ky=0;ky<KYC;ky++) fr[ky] = fp[ky*8];
    }
    __syncthreads();
  }
  float wreg[WID];
  #pragma unroll
  for(int cc=0;cc<WID;cc++) wreg[cc] = wcv[oid*WID + cc];
  float breg = bcv[oid];
  for(int i=tid;i<KT*NT;i+=256){
    int k=i/NT, t=i-k*NT;
    float ang = TWO_PI*(float)((k*t)%NT)/(float)NT;
    float sc = (k==0 ? 1.0f : 2.0f)*(1.0f/(float)NT);
    tcts[i] = make_float2(cosf(ang)*sc, sinf(ang)*sc);
  }
  for(int i=tid;i<32*KYC;i+=256){
    int yy=i/KYC, ky=i-yy*KYC;
    int f = ky<M1C ? ky : ky+40;
    float ang = TWO_PI*(float)((f*(y0+yy))%NY)/(float)NY;
    twy[i] = make_float2(cosf(ang)*(1.0f/64.0f), sinf(ang)*(1.0f/64.0f));
  }
  float* plane = V + (size_t)((b*NX+x)*NY + y0)*(NT*WID);
  const float4* gp = (const float4*)plane;
  bool has2 = tid < 64;
  // prologue fill of vt0 (y=0): linear chunks
  float4 g0 = gp[tid];
  float4 g1 = has2 ? gp[256+tid] : make_float4(0,0,0,0);
  ((float4*)vt0)[tid] = g0;
  if(has2) ((float4*)vt0)[256+tid] = g1;
  __syncthreads();

  for(int y=0;y<32;y++){
    if(y+1 < 32){                         // prefetch next plane (in flight across barrier)
      g0 = gp[(size_t)(y+1)*320 + tid];
      if(has2) g1 = gp[(size_t)(y+1)*320 + 256 + tid];
    }
    { // inverse-Y in registers -> ftc[kt][c]
      const float2* tw = twy + y*KYC;
      float sr=0.f, si=0.f;
      #pragma unroll
      for(int ky=0;ky<KYC;ky++){
        float2 w = tw[ky];
        float2 a = fr[ky];
        sr += a.x*w.x - a.y*w.y;
        si += a.x*w.y + a.y*w.x;
      }
      ftc[ktid*32 + cid] = make_float2(sr,si);
    }
    barrier_lds();
    { // conv1x1 + irfft-T; direct full-line stores
      float2 fR[KT];
      #pragma unroll
      for(int k=0;k<KT;k++) fR[k] = ftc[k*32 + oid];
      const float* vb = (y&1) ? vt1 : vt0;
      float* outp = plane + (size_t)y*(NT*WID);
      #pragma unroll
      for(int j=0;j<5;j++){
        int t = tg*5 + j;
        float a = breg;
        const float* vrow = vb + t*32;
        #pragma unroll
        for(int c4=0;c4<WID;c4+=4){
          float4 vv = *(const float4*)(vrow + c4);   // broadcast b128
          a += vv.x*wreg[c4] + vv.y*wreg[c4+1] + vv.z*wreg[c4+2] + vv.w*wreg[c4+3];
        }
        #pragma unroll
        for(int k=0;k<KT;k++){
          float2 w = tcts[k*NT + t];
          a += fR[k].x*w.x - fR[k].y*w.y;
        }
        outp[t*32 + oid] = GELU ? gelu_f(a) : a;     // lanes 0-31: one full 128B line
      }
    }
    if(y+1 < 32){
      float* d = (y&1) ? vt0 : vt1;
      ((float4*)d)[tid] = g0;
      if(has2) ((float4*)d)[256+tid] = g1;
    }
    barrier_lds();
  }
}

// ---------------- fused fc1+gelu+fc2: V -> out [B,X,Y,T,2] ----------------
__global__ __launch_bounds__(256) void k_mlp(const float* __restrict__ V, const float* __restrict__ w1,
                                             const float* __restrict__ b1, const float* __restrict__ w2,
                                             const float* __restrict__ b2, float* __restrict__ out){
  __shared__ float sw1[WID*64];
  __shared__ float sb1[64], sw2[128], sb2[2];
  int tid=threadIdx.x;
  for(int i=tid;i<WID*64;i+=256) sw1[i]=w1[i];
  if(tid<64) sb1[tid]=b1[tid];
  if(tid<128) sw2[tid]=w2[tid];
  if(tid<2) sb2[tid]=b2[tid];
  __syncthreads();
  int p = blockIdx.x*256 + tid;
  float vcol[WID];
  const float4* vp = (const float4*)(V + (size_t)p*WID);
  #pragma unroll
  for(int q=0;q<8;q++){
    float4 vv = vp[q];
    vcol[4*q]=vv.x; vcol[4*q+1]=vv.y; vcol[4*q+2]=vv.z; vcol[4*q+3]=vv.w;
  }
  float o0=sb2[0], o1=sb2[1];
  #pragma unroll 2
  for(int j=0;j<64;j++){
    float a=sb1[j];
    #pragma unroll
    for(int cc=0;cc<WID;cc++) a += vcol[cc]*sw1[cc*64+j];
    a = gelu_f(a);
    o0 += a*sw2[2*j]; o1 += a*sw2[2*j+1];
  }
  ((float2*)out)[p]=make_float2(o0,o1);
}

extern "C" void kernel_launch(void* const* d_in, const int* in_sizes, int n_in,
                              void* d_out, int out_size, void* d_ws, size_t ws_size,
                              hipStream_t stream){
  const float* h     = (const float*)d_in[0];
  const float* x     = (const float*)d_in[1];
  const float* fc0_w = (const float*)d_in[2];
  const float* fc0_b = (const float*)d_in[3];
  const float* scwr[3] = {(const float*)d_in[4], (const float*)d_in[6], (const float*)d_in[8]};
  const float* scwi[3] = {(const float*)d_in[5], (const float*)d_in[7], (const float*)d_in[9]};
  const float* cw[3]   = {(const float*)d_in[10], (const float*)d_in[12], (const float*)d_in[14]};
  const float* cb[3]   = {(const float*)d_in[11], (const float*)d_in[13], (const float*)d_in[15]};
  const float* fc1_w = (const float*)d_in[16];
  const float* fc1_b = (const float*)d_in[17];
  const float* fc2_w = (const float*)d_in[18];
  const float* fc2_b = (const float*)d_in[19];

  // workspace: V (167.8 MB, layout [b,x,y,t,c]) | F2 (25.2 MB) | F4 (9.4 MB)
  // F3 lives in d_out (9.4 MB <= 10.5 MB) until k_mlp overwrites it.
  const size_t VSZ = (size_t)BATCH*WID*NXYT;
  float*  V  = (float*)d_ws;
  float2* F2 = (float2*)(V + VSZ);
  float2* F4 = F2 + (size_t)BATCH*WID*NX*KYC*KT;
  float2* F3 = (float2*)d_out;

  k_fc0<<<NP/32, 256, 0, stream>>>(h, x, fc0_w, fc0_b, V);
  for(int L=0; L<3; L++){
    k_fwd_ty<<<BATCH*NX, 256, 0, stream>>>(V, F2);
    k_fwd_x<<<(BATCH*WID)*KYC, 256, 0, stream>>>(F2, F3);
    k_mix<<<(BATCH*WID*KXC*KYC*KT)/256, 256, 0, stream>>>(F3, scwr[L], scwi[L], F4);
    k_inv_x<<<(BATCH*WID)*KYC, 256, 0, stream>>>(F4, F2);
    if(L<2) k_conv<true ><<<BATCH*NX*2, 256, 0, stream>>>(F2, cw[L], cb[L], V);
    else    k_conv<false><<<BATCH*NX*2, 256, 0, stream>>>(F2, cw[L], cb[L], V);
  }
  k_mlp<<<NP/256, 256, 0, stream>>>(V, fc1_w, fc1_b, fc2_w, fc2_b, (float*)d_out);
}

// Round 7
// 1671.629 us; speedup vs baseline: 1.5515x; 1.0212x over previous
//
#include <hip/hip_runtime.h>
#include <math.h>

#define BATCH 8
#define WID   32
#define NX    64
#define NY    64
#define NT    40
#define M1C   12
#define KT    8      // M3
#define KXC   24
#define KYC   24
#define NXY   (NX*NY)        // 4096
#define NXYT  (NXY*NT)       // 163840
#define NP    (BATCH*NXYT)   // 1310720

#define TWO_PI 6.283185307179586f

static __device__ __forceinline__ float gelu_f(float v){
  return 0.5f*v*(1.0f + erff(v*0.7071067811865476f));
}

// barrier that does NOT drain vmcnt (keeps global prefetch loads in flight).
static __device__ __forceinline__ void barrier_lds(){
  asm volatile("s_waitcnt lgkmcnt(0)\n\ts_barrier" ::: "memory");
}

// V layout throughout: [b][x][y][t][c]  (channel-innermost, plane = 1280 floats)

// ---------------- fc0: [B,X,Y,T,5] -> V ----------------
__global__ __launch_bounds__(256) void k_fc0(const float* __restrict__ h, const float* __restrict__ x,
                                             const float* __restrict__ w, const float* __restrict__ b,
                                             float* __restrict__ V){
  __shared__ float sw[160], sb[32];
  int tid=threadIdx.x;
  if(tid<160) sw[tid]=w[tid];
  if(tid<32)  sb[tid]=b[tid];
  __syncthreads();
  int pl = tid>>3, q = tid&7;
  int p = blockIdx.x*32 + pl;
  float i0=h[(size_t)p*2], i1=h[(size_t)p*2+1];
  float i2=x[(size_t)p*3], i3=x[(size_t)p*3+1], i4=x[(size_t)p*3+2];
  int c0=q*4;
  float4 o;
  float* po=(float*)&o;
  #pragma unroll
  for(int u=0;u<4;u++){
    int c=c0+u;
    po[u] = sb[c] + i0*sw[c] + i1*sw[32+c] + i2*sw[64+c] + i3*sw[96+c] + i4*sw[128+c];
  }
  ((float4*)V)[(size_t)p*8 + q] = o;
}

// ------- fused forward T+Y per (b,x): V slice -> F2 [bc*64+x][ky*8+kt] -------
__global__ __launch_bounds__(256) void k_fwd_ty(const float* __restrict__ V, float2* __restrict__ F2){
  __shared__ __align__(16) unsigned char smem[64256];
  float*  vt    = (float*)smem;                 // 10240 floats (one 8-y group)
  float2* f2out = (float2*)smem;                // alias (after last compute): 32*193
  float2* twt   = (float2*)(smem + 49408);      // 8*40
  float2* twy   = (float2*)(smem + 51968);      // 24*64
  int tid = threadIdx.x;
  int b = blockIdx.x >> 6, x = blockIdx.x & 63;
  int c = tid & 31, k = tid >> 5;
  for(int i=tid;i<KT*NT;i+=256){
    int kk=i/NT, t=i-kk*NT;
    float ang = -TWO_PI*(float)((kk*t)%NT)/(float)NT;
    twt[i] = make_float2(cosf(ang), sinf(ang));
  }
  for(int i=tid;i<KYC*NY;i+=256){
    int ky=i/NY, y=i-ky*NY;
    int f = ky<M1C ? ky : ky+40;
    float ang = -TWO_PI*(float)((f*y)%NY)/(float)NY;
    twy[i] = make_float2(cosf(ang), sinf(ang));
  }
  float2 acc[KYC];
  #pragma unroll
  for(int ky=0;ky<KYC;ky++) acc[ky]=make_float2(0.f,0.f);
  const float4* src = (const float4*)(V + (size_t)(b*NX+x)*(NY*NT*WID));
  for(int g=0; g<8; g++){
    __syncthreads();                       // prev compute / table init done
    #pragma unroll
    for(int r=0;r<10;r++) ((float4*)vt)[r*256+tid] = src[g*2560 + r*256 + tid];
    __syncthreads();
    for(int yl=0; yl<8; yl++){
      float sr=0.f, si=0.f;
      const float* vp = vt + yl*1280 + c;
      const float2* tw = twt + k*NT;
      #pragma unroll 8
      for(int t=0;t<NT;t++){
        float v = vp[t*32];                // lanes 0-31 contiguous; 32-63 broadcast
        float2 w = tw[t];
        sr += v*w.x; si += v*w.y;
      }
      int y = g*8 + yl;
      #pragma unroll
      for(int ky=0;ky<KYC;ky++){
        float2 wy = twy[ky*NY + y];
        acc[ky].x += sr*wy.x - si*wy.y;
        acc[ky].y += sr*wy.y + si*wy.x;
      }
    }
  }
  __syncthreads();                         // vt dead -> f2out alias safe
  #pragma unroll
  for(int ky=0;ky<KYC;ky++) f2out[c*193 + ky*KT + k] = acc[ky];
  __syncthreads();
  for(int i=tid;i<WID*KYC*KT;i+=256){
    int cc=i/192, e=i-cc*192;
    F2[((size_t)(b*WID+cc)*NX + x)*(KYC*KT) + e] = f2out[cc*193 + e];
  }
}

// ---------------- forward X: F2 -> F3 [B,32,24,24,8] cplx ----------------
__global__ __launch_bounds__(256) void k_fwd_x(const float2* __restrict__ F2, float2* __restrict__ F3){
  __shared__ float2 tile[NX*KT];
  __shared__ float twc[KXC*65], tws[KXC*65];
  int tid=threadIdx.x;
  int bc = blockIdx.x / KYC;
  int ky = blockIdx.x - bc*KYC;
  for(int i=tid;i<NX*KT;i+=256){
    int xx=i/KT, kt=i-xx*KT;
    tile[i] = F2[((size_t)bc*NX + xx)*(KYC*KT) + ky*KT + kt];
  }
  for(int i=tid;i<KXC*NX;i+=256){
    int kx=i/NX, xx=i-kx*NX;
    int f = kx<M1C ? kx : kx+40;
    float ang = -TWO_PI*(float)((f*xx)%NX)/(float)NX;
    twc[kx*65+xx]=cosf(ang); tws[kx*65+xx]=sinf(ang);
  }
  __syncthreads();
  for(int item=tid; item<KXC*KT; item+=256){
    int kx=item/KT, kt=item-kx*KT;
    float sr=0.f, si=0.f;
    #pragma unroll 8
    for(int xx=0;xx<NX;xx++){
      float2 a = tile[xx*KT+kt];
      float c = twc[kx*65+xx], s = tws[kx*65+xx];
      sr += a.x*c - a.y*s;
      si += a.x*s + a.y*c;
    }
    F3[(size_t)bc*(KXC*KYC*KT) + kx*(KYC*KT) + ky*KT + kt] = make_float2(sr,si);
  }
}

// ---------------- channel mix: F3 -> F4 ----------------
// block = one (kx,ky) pair = 8 kt modes; thread = (o, kt). Weights in
// registers (read once per layer); F3 tile staged in LDS (read once, reused
// across the 32 output channels) instead of 32x global re-reads.
__global__ __launch_bounds__(256) void k_mix(const float2* __restrict__ F3, const float* __restrict__ wr,
                                             const float* __restrict__ wi, float2* __restrict__ F4){
  __shared__ float2 f3s[BATCH*WID*KT];     // [b][i][kt] = 16 KB
  int tid = threadIdx.x;
  int kx = blockIdx.x / KYC, ky = blockIdx.x - kx*KYC;
  int mode0 = blockIdx.x * KT;
  int xp = (kx>=M1C), yp = (ky>=M1C);
  int m1 = kx - M1C*xp, m2 = ky - M1C*yp;
  int blk = xp + 2*yp;
  // stage F3 tile: 256 rows (b*32+i) x 8 float2 = 1024 float4, coalesced 64B chunks
  for(int i=tid;i<1024;i+=256){
    int row=i>>2, q=i&3;
    ((float4*)f3s)[row*4+q] = ((const float4*)(F3 + (size_t)row*4608 + mode0))[q];
  }
  int o = tid>>3, kt = tid&7;
  size_t wbase = (size_t)blk*1179648 + (size_t)o*1152 + m1*96 + m2*8 + kt;
  float wre[WID], wim[WID];
  #pragma unroll
  for(int i=0;i<WID;i++){
    wre[i] = wr[wbase + (size_t)i*36864];
    wim[i] = wi[wbase + (size_t)i*36864];
  }
  __syncthreads();
  #pragma unroll
  for(int b=0;b<BATCH;b++){
    float ar=0.f, ai=0.f;
    #pragma unroll
    for(int i=0;i<WID;i++){
      float2 a = f3s[(b*WID+i)*KT + kt];
      ar += a.x*wre[i] - a.y*wim[i];
      ai += a.x*wim[i] + a.y*wre[i];
    }
    F4[(size_t)(b*WID+o)*4608 + mode0 + kt] = make_float2(ar,ai);
  }
}

// ---------------- inverse X: F4 -> F2 (1/64 folded) ----------------
__global__ __launch_bounds__(256) void k_inv_x(const float2* __restrict__ F4, float2* __restrict__ F2){
  __shared__ float2 tile[KXC*KT];
  __shared__ float twc[NX*KXC], tws[NX*KXC];
  int tid=threadIdx.x;
  int bc = blockIdx.x / KYC, ky = blockIdx.x - (blockIdx.x/KYC)*KYC;
  for(int i=tid;i<KXC*KT;i+=256){
    int kx=i/KT, kt=i-kx*KT;
    tile[i] = F4[(size_t)bc*4608 + kx*(KYC*KT) + ky*KT + kt];
  }
  for(int i=tid;i<NX*KXC;i+=256){
    int xx=i/KXC, kx=i-xx*KXC;
    int f = kx<M1C ? kx : kx+40;
    float ang = TWO_PI*(float)((f*xx)%NX)/(float)NX;
    twc[i]=cosf(ang)*(1.0f/64.0f); tws[i]=sinf(ang)*(1.0f/64.0f);
  }
  __syncthreads();
  for(int item=tid; item<NX*KT; item+=256){
    int xx=item/KT, kt=item-xx*KT;
    float sr=0.f, si=0.f;
    #pragma unroll 8
    for(int kx=0;kx<KXC;kx++){
      float2 a = tile[kx*KT+kt];
      float c = twc[xx*KXC+kx], s = tws[xx*KXC+kx];
      sr += a.x*c - a.y*s;
      si += a.x*s + a.y*c;
    }
    F2[((size_t)bc*NX + xx)*(KYC*KT) + ky*KT + kt] = make_float2(sr,si);
  }
}

// ------- fused inv-Y + irfft-T + conv1x1 [+gelu], in-place on V -------
// grid = B*NX*2, block = (b, x, y-half). NOTE: no min-waves clamp — the kernel
// needs ~130 VGPRs (fr[24]c + wreg[32] + prefetch); clamping to (256,4) forced
// VGPR=64 and spilled fr/wreg to scratch = 1.3 GB/dispatch of fetch (R3-R5 bug).
template<bool GELU>
__global__ __launch_bounds__(256) void k_conv(const float2* __restrict__ F2, const float* __restrict__ wcv,
                                              const float* __restrict__ bcv, float* __restrict__ V){
  __shared__ __align__(16) unsigned char smem[24576];
  float*  vt0  = (float*)smem;                  // 5120 B
  float*  vt1  = (float*)(smem+5120);           // 5120 B
  float2* ftc  = (float2*)(smem+10240);         // 2048 B
  float2* tcts = (float2*)(smem+12288);         // 2560 B
  float2* twy  = (float2*)(smem+14848);         // 6144 B (end 20992)
  float2* f2h  = (float2*)smem;                 // prologue alias: 24576 B

  int tid=threadIdx.x;
  int b  = blockIdx.x >> 7;
  int x  = (blockIdx.x >> 1) & 63;
  int y0 = (blockIdx.x & 1) * 32;
  int cid = tid & 31, ktid = tid >> 5;   // inv-Y identity
  int oid = tid & 31, tg  = tid >> 5;    // conv identity; t = tg*5+j

  // ---- prologue: F2 slice -> registers via LDS (two halves) ----
  float2 fr[KYC];
  #pragma unroll
  for(int half=0; half<2; half++){
    for(int i=tid;i<1536;i+=256){
      int cc=i/96, q=i-cc*96;
      ((float4*)f2h)[i] = *((const float4*)(F2 + ((size_t)(b*WID + half*16 + cc)*NX + x)*(KYC*KT)) + q);
    }
    __syncthreads();
    if((cid>>4) == half){
      const float2* fp = f2h + (cid&15)*192 + ktid;
      #pragma unroll
      for(int ky=0;ky<KYC;ky++) fr[ky] = fp[ky*8];
    }
    __syncthreads();
  }
  float wreg[WID];
  #pragma unroll
  for(int cc=0;cc<WID;cc++) wreg[cc] = wcv[oid*WID + cc];
  float breg = bcv[oid];
  for(int i=tid;i<KT*NT;i+=256){
    int k=i/NT, t=i-k*NT;
    float ang = TWO_PI*(float)((k*t)%NT)/(float)NT;
    float sc = (k==0 ? 1.0f : 2.0f)*(1.0f/(float)NT);
    tcts[i] = make_float2(cosf(ang)*sc, sinf(ang)*sc);
  }
  for(int i=tid;i<32*KYC;i+=256){
    int yy=i/KYC, ky=i-yy*KYC;
    int f = ky<M1C ? ky : ky+40;
    float ang = TWO_PI*(float)((f*(y0+yy))%NY)/(float)NY;
    twy[i] = make_float2(cosf(ang)*(1.0f/64.0f), sinf(ang)*(1.0f/64.0f));
  }
  float* plane = V + (size_t)((b*NX+x)*NY + y0)*(NT*WID);
  const float4* gp = (const float4*)plane;
  bool has2 = tid < 64;
  // prologue fill of vt0 (y=0): linear chunks
  float4 g0 = gp[tid];
  float4 g1 = has2 ? gp[256+tid] : make_float4(0,0,0,0);
  ((float4*)vt0)[tid] = g0;
  if(has2) ((float4*)vt0)[256+tid] = g1;
  __syncthreads();

  for(int y=0;y<32;y++){
    if(y+1 < 32){                         // prefetch next plane (in flight across barrier)
      g0 = gp[(size_t)(y+1)*320 + tid];
      if(has2) g1 = gp[(size_t)(y+1)*320 + 256 + tid];
    }
    { // inverse-Y in registers -> ftc[kt][c]
      const float2* tw = twy + y*KYC;
      float sr=0.f, si=0.f;
      #pragma unroll
      for(int ky=0;ky<KYC;ky++){
        float2 w = tw[ky];
        float2 a = fr[ky];
        sr += a.x*w.x - a.y*w.y;
        si += a.x*w.y + a.y*w.x;
      }
      ftc[ktid*32 + cid] = make_float2(sr,si);
    }
    barrier_lds();
    { // conv1x1 + irfft-T; direct full-line stores
      float2 fR[KT];
      #pragma unroll
      for(int k=0;k<KT;k++) fR[k] = ftc[k*32 + oid];
      const float* vb = (y&1) ? vt1 : vt0;
      float* outp = plane + (size_t)y*(NT*WID);
      #pragma unroll
      for(int j=0;j<5;j++){
        int t = tg*5 + j;
        float a = breg;
        const float* vrow = vb + t*32;
        #pragma unroll
        for(int c4=0;c4<WID;c4+=4){
          float4 vv = *(const float4*)(vrow + c4);   // broadcast b128
          a += vv.x*wreg[c4] + vv.y*wreg[c4+1] + vv.z*wreg[c4+2] + vv.w*wreg[c4+3];
        }
        #pragma unroll
        for(int k=0;k<KT;k++){
          float2 w = tcts[k*NT + t];
          a += fR[k].x*w.x - fR[k].y*w.y;
        }
        outp[t*32 + oid] = GELU ? gelu_f(a) : a;     // lanes 0-31: one full 128B line
      }
    }
    if(y+1 < 32){
      float* d = (y&1) ? vt0 : vt1;
      ((float4*)d)[tid] = g0;
      if(has2) ((float4*)d)[256+tid] = g1;
    }
    barrier_lds();
  }
}

// ---------------- fused fc1+gelu+fc2: V -> out [B,X,Y,T,2] ----------------
// 4 points/thread (vv[128] in regs) + w1 transposed [j][c] in LDS read as
// broadcast b128: LDS instr/point 2048 -> 128 (the R6 mlp was LDS-issue-bound).
__global__ __launch_bounds__(256) void k_mlp(const float* __restrict__ V, const float* __restrict__ w1,
                                             const float* __restrict__ b1, const float* __restrict__ w2,
                                             const float* __restrict__ b2, float* __restrict__ out){
  __shared__ float sw1t[64*WID];          // [j][c]
  __shared__ float sb1[64], sw2[128], sb2[2];
  int tid=threadIdx.x;
  for(int i=tid;i<64*WID;i+=256){ int j=i>>5, c=i&31; sw1t[i]=w1[c*64+j]; }
  if(tid<64) sb1[tid]=b1[tid];
  if(tid<128) sw2[tid]=w2[tid];
  if(tid<2) sb2[tid]=b2[tid];
  __syncthreads();
  size_t p0 = (size_t)blockIdx.x*1024 + (size_t)tid*4;
  float vv[128];
  const float4* vp = (const float4*)(V + p0*WID);
  #pragma unroll
  for(int q=0;q<32;q++) *((float4*)(vv+4*q)) = vp[q];
  float oa[8];
  #pragma unroll
  for(int pt=0;pt<4;pt++){ oa[2*pt]=sb2[0]; oa[2*pt+1]=sb2[1]; }
  #pragma unroll 4
  for(int j=0;j<64;j++){
    float a0=sb1[j], a1=a0, a2=a0, a3=a0;
    const float* wrow = sw1t + j*WID;
    #pragma unroll
    for(int c4=0;c4<WID;c4+=4){
      float4 w = *(const float4*)(wrow + c4);        // broadcast b128
      a0 += vv[     c4]*w.x + vv[     c4+1]*w.y + vv[     c4+2]*w.z + vv[     c4+3]*w.w;
      a1 += vv[32 + c4]*w.x + vv[32 + c4+1]*w.y + vv[32 + c4+2]*w.z + vv[32 + c4+3]*w.w;
      a2 += vv[64 + c4]*w.x + vv[64 + c4+1]*w.y + vv[64 + c4+2]*w.z + vv[64 + c4+3]*w.w;
      a3 += vv[96 + c4]*w.x + vv[96 + c4+1]*w.y + vv[96 + c4+2]*w.z + vv[96 + c4+3]*w.w;
    }
    a0=gelu_f(a0); a1=gelu_f(a1); a2=gelu_f(a2); a3=gelu_f(a3);
    float u0=sw2[2*j], u1=sw2[2*j+1];
    oa[0]+=a0*u0; oa[1]+=a0*u1; oa[2]+=a1*u0; oa[3]+=a1*u1;
    oa[4]+=a2*u0; oa[5]+=a2*u1; oa[6]+=a3*u0; oa[7]+=a3*u1;
  }
  float4* op = (float4*)(out + p0*2);
  op[0]=make_float4(oa[0],oa[1],oa[2],oa[3]);
  op[1]=make_float4(oa[4],oa[5],oa[6],oa[7]);
}

extern "C" void kernel_launch(void* const* d_in, const int* in_sizes, int n_in,
                              void* d_out, int out_size, void* d_ws, size_t ws_size,
                              hipStream_t stream){
  const float* h     = (const float*)d_in[0];
  const float* x     = (const float*)d_in[1];
  const float* fc0_w = (const float*)d_in[2];
  const float* fc0_b = (const float*)d_in[3];
  const float* scwr[3] = {(const float*)d_in[4], (const float*)d_in[6], (const float*)d_in[8]};
  const float* scwi[3] = {(const float*)d_in[5], (const float*)d_in[7], (const float*)d_in[9]};
  const float* cw[3]   = {(const float*)d_in[10], (const float*)d_in[12], (const float*)d_in[14]};
  const float* cb[3]   = {(const float*)d_in[11], (const float*)d_in[13], (const float*)d_in[15]};
  const float* fc1_w = (const float*)d_in[16];
  const float* fc1_b = (const float*)d_in[17];
  const float* fc2_w = (const float*)d_in[18];
  const float* fc2_b = (const float*)d_in[19];

  // workspace: V (167.8 MB, layout [b,x,y,t,c]) | F2 (25.2 MB) | F4 (9.4 MB)
  // F3 lives in d_out (9.4 MB <= 10.5 MB) until k_mlp overwrites it.
  const size_t VSZ = (size_t)BATCH*WID*NXYT;
  float*  V  = (float*)d_ws;
  float2* F2 = (float2*)(V + VSZ);
  float2* F4 = F2 + (size_t)BATCH*WID*NX*KYC*KT;
  float2* F3 = (float2*)d_out;

  k_fc0<<<NP/32, 256, 0, stream>>>(h, x, fc0_w, fc0_b, V);
  for(int L=0; L<3; L++){
    k_fwd_ty<<<BATCH*NX, 256, 0, stream>>>(V, F2);
    k_fwd_x<<<(BATCH*WID)*KYC, 256, 0, stream>>>(F2, F3);
    k_mix<<<KXC*KYC, 256, 0, stream>>>(F3, scwr[L], scwi[L], F4);
    k_inv_x<<<(BATCH*WID)*KYC, 256, 0, stream>>>(F4, F2);
    if(L<2) k_conv<true ><<<BATCH*NX*2, 256, 0, stream>>>(F2, cw[L], cb[L], V);
    else    k_conv<false><<<BATCH*NX*2, 256, 0, stream>>>(F2, cw[L], cb[L], V);
  }
  k_mlp<<<NP/1024, 256, 0, stream>>>(V, fc1_w, fc1_b, fc2_w, fc2_b, (float*)d_out);
}

// Round 8
// 1586.687 us; speedup vs baseline: 1.6346x; 1.0535x over previous
//
#include <hip/hip_runtime.h>
#include <math.h>

#define BATCH 8
#define WID   32
#define NX    64
#define NY    64
#define NT    40
#define M1C   12
#define KT    8      // M3
#define KXC   24
#define KYC   24
#define NXY   (NX*NY)        // 4096
#define NXYT  (NXY*NT)       // 163840
#define NP    (BATCH*NXYT)   // 1310720

#define TWO_PI 6.283185307179586f

static __device__ __forceinline__ float gelu_f(float v){
  return 0.5f*v*(1.0f + erff(v*0.7071067811865476f));
}

// barrier that does NOT drain vmcnt (keeps global prefetch loads in flight).
static __device__ __forceinline__ void barrier_lds(){
  asm volatile("s_waitcnt lgkmcnt(0)\n\ts_barrier" ::: "memory");
}

// V layout throughout: [b][x][y][t][c]  (channel-innermost, plane = 1280 floats)

// ---------------- fc0: [B,X,Y,T,5] -> V ----------------
__global__ __launch_bounds__(256) void k_fc0(const float* __restrict__ h, const float* __restrict__ x,
                                             const float* __restrict__ w, const float* __restrict__ b,
                                             float* __restrict__ V){
  __shared__ float sw[160], sb[32];
  int tid=threadIdx.x;
  if(tid<160) sw[tid]=w[tid];
  if(tid<32)  sb[tid]=b[tid];
  __syncthreads();
  int pl = tid>>3, q = tid&7;
  int p = blockIdx.x*32 + pl;
  float i0=h[(size_t)p*2], i1=h[(size_t)p*2+1];
  float i2=x[(size_t)p*3], i3=x[(size_t)p*3+1], i4=x[(size_t)p*3+2];
  int c0=q*4;
  float4 o;
  float* po=(float*)&o;
  #pragma unroll
  for(int u=0;u<4;u++){
    int c=c0+u;
    po[u] = sb[c] + i0*sw[c] + i1*sw[32+c] + i2*sw[64+c] + i3*sw[96+c] + i4*sw[128+c];
  }
  ((float4*)V)[(size_t)p*8 + q] = o;
}

// ------- fused forward T+Y per (b,x): V slice -> F2 [bc*64+x][ky*8+kt] -------
// T-twiddles in REGISTERS (per-thread k row, 40 cplx); Y-twiddles read as
// float4 pairs (2 y at once). Cuts LDS instr per y from 104 to ~52 (was
// LDS-issue-bound at ~744 LDS-pipe cyc/y vs 352 VALU).
__global__ __launch_bounds__(256) void k_fwd_ty(const float* __restrict__ V, float2* __restrict__ F2){
  __shared__ __align__(16) unsigned char smem[61696];
  float*  vt    = (float*)smem;                 // 10240 floats (one 8-y group), 40960 B
  float2* f2out = (float2*)smem;                // alias (after last compute): 32*193 = 49408 B
  float2* twy   = (float2*)(smem + 49408);      // [ky][64 y] = 12288 B
  int tid = threadIdx.x;
  int b = blockIdx.x >> 6, x = blockIdx.x & 63;
  int c = tid & 31, k = tid >> 5;
  for(int i=tid;i<KYC*NY;i+=256){
    int ky=i/NY, y=i-ky*NY;
    int f = ky<M1C ? ky : ky+40;
    float ang = -TWO_PI*(float)((f*y)%NY)/(float)NY;
    twy[ky*NY+y] = make_float2(cosf(ang), sinf(ang));
  }
  // per-thread T-twiddle row (k fixed per thread)
  float2 twr[NT];
  #pragma unroll
  for(int t=0;t<NT;t++){
    float ang = -TWO_PI*(float)((k*t)%NT)/(float)NT;
    twr[t] = make_float2(cosf(ang), sinf(ang));
  }
  float2 acc[KYC];
  #pragma unroll
  for(int ky=0;ky<KYC;ky++) acc[ky]=make_float2(0.f,0.f);
  const float4* src = (const float4*)(V + (size_t)(b*NX+x)*(NY*NT*WID));
  for(int g=0; g<8; g++){
    __syncthreads();                       // prev compute / table init done
    #pragma unroll
    for(int r=0;r<10;r++) ((float4*)vt)[r*256+tid] = src[g*2560 + r*256 + tid];
    __syncthreads();
    for(int yl=0; yl<8; yl+=2){
      float sr0=0.f, si0=0.f, sr1=0.f, si1=0.f;
      const float* vp0 = vt + yl*1280 + c;
      const float* vp1 = vp0 + 1280;
      #pragma unroll
      for(int t=0;t<NT;t++){
        float2 w = twr[t];
        float v0 = vp0[t*32];              // 32 distinct addrs = all banks; upper half broadcast
        float v1 = vp1[t*32];
        sr0 += v0*w.x; si0 += v0*w.y;
        sr1 += v1*w.x; si1 += v1*w.y;
      }
      int y = g*8 + yl;
      #pragma unroll
      for(int ky=0;ky<KYC;ky++){
        float4 wy = *(const float4*)&twy[ky*NY + y];   // (w_y, w_{y+1}) one b128
        acc[ky].x += sr0*wy.x - si0*wy.y + sr1*wy.z - si1*wy.w;
        acc[ky].y += sr0*wy.y + si0*wy.x + sr1*wy.w + si1*wy.z;
      }
    }
  }
  __syncthreads();                         // vt dead -> f2out alias safe
  #pragma unroll
  for(int ky=0;ky<KYC;ky++) f2out[c*193 + ky*KT + k] = acc[ky];
  __syncthreads();
  for(int i=tid;i<WID*KYC*KT;i+=256){
    int cc=i/192, e=i-cc*192;
    F2[((size_t)(b*WID+cc)*NX + x)*(KYC*KT) + e] = f2out[cc*193 + e];
  }
}

// ---------------- forward X: F2 -> F3 [B,32,24,24,8] cplx ----------------
// twiddles interleaved as float2: 1 b64 read per MAC step (was 2 b32).
__global__ __launch_bounds__(256) void k_fwd_x(const float2* __restrict__ F2, float2* __restrict__ F3){
  __shared__ float2 tile[NX*KT];
  __shared__ float2 twi[KXC*65];          // stride 65 cplx
  int tid=threadIdx.x;
  int bc = blockIdx.x / KYC;
  int ky = blockIdx.x - bc*KYC;
  for(int i=tid;i<NX*KT;i+=256){
    int xx=i/KT, kt=i-xx*KT;
    tile[i] = F2[((size_t)bc*NX + xx)*(KYC*KT) + ky*KT + kt];
  }
  for(int i=tid;i<KXC*NX;i+=256){
    int kx=i/NX, xx=i-kx*NX;
    int f = kx<M1C ? kx : kx+40;
    float ang = -TWO_PI*(float)((f*xx)%NX)/(float)NX;
    twi[kx*65+xx] = make_float2(cosf(ang), sinf(ang));
  }
  __syncthreads();
  for(int item=tid; item<KXC*KT; item+=256){
    int kx=item/KT, kt=item-kx*KT;
    float sr=0.f, si=0.f;
    #pragma unroll 8
    for(int xx=0;xx<NX;xx++){
      float2 a = tile[xx*KT+kt];
      float2 w = twi[kx*65+xx];
      sr += a.x*w.x - a.y*w.y;
      si += a.x*w.y + a.y*w.x;
    }
    F3[(size_t)bc*(KXC*KYC*KT) + kx*(KYC*KT) + ky*KT + kt] = make_float2(sr,si);
  }
}

// ---------------- channel mix: F3 -> F4 ----------------
__global__ __launch_bounds__(256) void k_mix(const float2* __restrict__ F3, const float* __restrict__ wr,
                                             const float* __restrict__ wi, float2* __restrict__ F4){
  __shared__ float2 f3s[BATCH*WID*KT];     // [b][i][kt] = 16 KB
  int tid = threadIdx.x;
  int kx = blockIdx.x / KYC, ky = blockIdx.x - kx*KYC;
  int mode0 = blockIdx.x * KT;
  int xp = (kx>=M1C), yp = (ky>=M1C);
  int m1 = kx - M1C*xp, m2 = ky - M1C*yp;
  int blk = xp + 2*yp;
  for(int i=tid;i<1024;i+=256){
    int row=i>>2, q=i&3;
    ((float4*)f3s)[row*4+q] = ((const float4*)(F3 + (size_t)row*4608 + mode0))[q];
  }
  int o = tid>>3, kt = tid&7;
  size_t wbase = (size_t)blk*1179648 + (size_t)o*1152 + m1*96 + m2*8 + kt;
  float wre[WID], wim[WID];
  #pragma unroll
  for(int i=0;i<WID;i++){
    wre[i] = wr[wbase + (size_t)i*36864];
    wim[i] = wi[wbase + (size_t)i*36864];
  }
  __syncthreads();
  #pragma unroll
  for(int b=0;b<BATCH;b++){
    float ar=0.f, ai=0.f;
    #pragma unroll
    for(int i=0;i<WID;i++){
      float2 a = f3s[(b*WID+i)*KT + kt];
      ar += a.x*wre[i] - a.y*wim[i];
      ai += a.x*wim[i] + a.y*wre[i];
    }
    F4[(size_t)(b*WID+o)*4608 + mode0 + kt] = make_float2(ar,ai);
  }
}

// ---------------- inverse X: F4 -> F2 (1/64 folded) ----------------
// twiddles interleaved float2, stride 25 (2-way bank aliasing = free).
__global__ __launch_bounds__(256) void k_inv_x(const float2* __restrict__ F4, float2* __restrict__ F2){
  __shared__ float2 tile[KXC*KT];
  __shared__ float2 twi[NX*25];
  int tid=threadIdx.x;
  int bc = blockIdx.x / KYC, ky = blockIdx.x - (blockIdx.x/KYC)*KYC;
  for(int i=tid;i<KXC*KT;i+=256){
    int kx=i/KT, kt=i-kx*KT;
    tile[i] = F4[(size_t)bc*4608 + kx*(KYC*KT) + ky*KT + kt];
  }
  for(int i=tid;i<NX*KXC;i+=256){
    int xx=i/KXC, kx=i-xx*KXC;
    int f = kx<M1C ? kx : kx+40;
    float ang = TWO_PI*(float)((f*xx)%NX)/(float)NX;
    twi[xx*25+kx] = make_float2(cosf(ang)*(1.0f/64.0f), sinf(ang)*(1.0f/64.0f));
  }
  __syncthreads();
  for(int item=tid; item<NX*KT; item+=256){
    int xx=item/KT, kt=item-xx*KT;
    float sr=0.f, si=0.f;
    #pragma unroll 8
    for(int kx=0;kx<KXC;kx++){
      float2 a = tile[kx*KT+kt];
      float2 w = twi[xx*25+kx];
      sr += a.x*w.x - a.y*w.y;
      si += a.x*w.y + a.y*w.x;
    }
    F2[((size_t)bc*NX + xx)*(KYC*KT) + ky*KT + kt] = make_float2(sr,si);
  }
}

// ------- fused inv-Y + irfft-T + conv1x1 [+gelu], in-place on V -------
// grid = B*NX*2, block = (b, x, y-half). NOTE: no min-waves clamp — the kernel
// needs ~130 VGPRs (fr[24]c + wreg[32] + prefetch); clamping to (256,4) forced
// VGPR=64 and spilled fr/wreg to scratch = 1.3 GB/dispatch of fetch (R3-R5 bug).
template<bool GELU>
__global__ __launch_bounds__(256) void k_conv(const float2* __restrict__ F2, const float* __restrict__ wcv,
                                              const float* __restrict__ bcv, float* __restrict__ V){
  __shared__ __align__(16) unsigned char smem[24576];
  float*  vt0  = (float*)smem;                  // 5120 B
  float*  vt1  = (float*)(smem+5120);           // 5120 B
  float2* ftc  = (float2*)(smem+10240);         // 2048 B
  float2* tcts = (float2*)(smem+12288);         // 2560 B
  float2* twy  = (float2*)(smem+14848);         // 6144 B (end 20992)
  float2* f2h  = (float2*)smem;                 // prologue alias: 24576 B

  int tid=threadIdx.x;
  int b  = blockIdx.x >> 7;
  int x  = (blockIdx.x >> 1) & 63;
  int y0 = (blockIdx.x & 1) * 32;
  int cid = tid & 31, ktid = tid >> 5;   // inv-Y identity
  int oid = tid & 31, tg  = tid >> 5;    // conv identity; t = tg*5+j

  // ---- prologue: F2 slice -> registers via LDS (two halves) ----
  float2 fr[KYC];
  #pragma unroll
  for(int half=0; half<2; half++){
    for(int i=tid;i<1536;i+=256){
      int cc=i/96, q=i-cc*96;
      ((float4*)f2h)[i] = *((const float4*)(F2 + ((size_t)(b*WID + half*16 + cc)*NX + x)*(KYC*KT)) + q);
    }
    __syncthreads();
    if((cid>>4) == half){
      const float2* fp = f2h + (cid&15)*192 + ktid;
      #pragma unroll
      for(int ky=0;ky<KYC;ky++) fr[ky] = fp[ky*8];
    }
    __syncthreads();
  }
  float wreg[WID];
  #pragma unroll
  for(int cc=0;cc<WID;cc++) wreg[cc] = wcv[oid*WID + cc];
  float breg = bcv[oid];
  for(int i=tid;i<KT*NT;i+=256){
    int k=i/NT, t=i-k*NT;
    float ang = TWO_PI*(float)((k*t)%NT)/(float)NT;
    float sc = (k==0 ? 1.0f : 2.0f)*(1.0f/(float)NT);
    tcts[i] = make_float2(cosf(ang)*sc, sinf(ang)*sc);
  }
  for(int i=tid;i<32*KYC;i+=256){
    int yy=i/KYC, ky=i-yy*KYC;
    int f = ky<M1C ? ky : ky+40;
    float ang = TWO_PI*(float)((f*(y0+yy))%NY)/(float)NY;
    twy[i] = make_float2(cosf(ang)*(1.0f/64.0f), sinf(ang)*(1.0f/64.0f));
  }
  float* plane = V + (size_t)((b*NX+x)*NY + y0)*(NT*WID);
  const float4* gp = (const float4*)plane;
  bool has2 = tid < 64;
  float4 g0 = gp[tid];
  float4 g1 = has2 ? gp[256+tid] : make_float4(0,0,0,0);
  ((float4*)vt0)[tid] = g0;
  if(has2) ((float4*)vt0)[256+tid] = g1;
  __syncthreads();

  for(int y=0;y<32;y++){
    if(y+1 < 32){                         // prefetch next plane (in flight across barrier)
      g0 = gp[(size_t)(y+1)*320 + tid];
      if(has2) g1 = gp[(size_t)(y+1)*320 + 256 + tid];
    }
    { // inverse-Y in registers -> ftc[kt][c]
      const float2* tw = twy + y*KYC;
      float sr=0.f, si=0.f;
      #pragma unroll
      for(int ky=0;ky<KYC;ky++){
        float2 w = tw[ky];
        float2 a = fr[ky];
        sr += a.x*w.x - a.y*w.y;
        si += a.x*w.y + a.y*w.x;
      }
      ftc[ktid*32 + cid] = make_float2(sr,si);
    }
    barrier_lds();
    { // conv1x1 + irfft-T; direct full-line stores
      float2 fR[KT];
      #pragma unroll
      for(int k=0;k<KT;k++) fR[k] = ftc[k*32 + oid];
      const float* vb = (y&1) ? vt1 : vt0;
      float* outp = plane + (size_t)y*(NT*WID);
      #pragma unroll
      for(int j=0;j<5;j++){
        int t = tg*5 + j;
        float a = breg;
        const float* vrow = vb + t*32;
        #pragma unroll
        for(int c4=0;c4<WID;c4+=4){
          float4 vv = *(const float4*)(vrow + c4);   // broadcast b128
          a += vv.x*wreg[c4] + vv.y*wreg[c4+1] + vv.z*wreg[c4+2] + vv.w*wreg[c4+3];
        }
        #pragma unroll
        for(int k=0;k<KT;k++){
          float2 w = tcts[k*NT + t];
          a += fR[k].x*w.x - fR[k].y*w.y;
        }
        outp[t*32 + oid] = GELU ? gelu_f(a) : a;     // lanes 0-31: one full 128B line
      }
    }
    if(y+1 < 32){
      float* d = (y&1) ? vt0 : vt1;
      ((float4*)d)[tid] = g0;
      if(has2) ((float4*)d)[256+tid] = g1;
    }
    barrier_lds();
  }
}

// ---------------- fused fc1+gelu+fc2: V -> out [B,X,Y,T,2] ----------------
__global__ __launch_bounds__(256) void k_mlp(const float* __restrict__ V, const float* __restrict__ w1,
                                             const float* __restrict__ b1, const float* __restrict__ w2,
                                             const float* __restrict__ b2, float* __restrict__ out){
  __shared__ float sw1t[64*WID];          // [j][c]
  __shared__ float sb1[64], sw2[128], sb2[2];
  int tid=threadIdx.x;
  for(int i=tid;i<64*WID;i+=256){ int j=i>>5, c=i&31; sw1t[i]=w1[c*64+j]; }
  if(tid<64) sb1[tid]=b1[tid];
  if(tid<128) sw2[tid]=w2[tid];
  if(tid<2) sb2[tid]=b2[tid];
  __syncthreads();
  size_t p0 = (size_t)blockIdx.x*1024 + (size_t)tid*4;
  float vv[128];
  const float4* vp = (const float4*)(V + p0*WID);
  #pragma unroll
  for(int q=0;q<32;q++) *((float4*)(vv+4*q)) = vp[q];
  float oa[8];
  #pragma unroll
  for(int pt=0;pt<4;pt++){ oa[2*pt]=sb2[0]; oa[2*pt+1]=sb2[1]; }
  #pragma unroll 4
  for(int j=0;j<64;j++){
    float a0=sb1[j], a1=a0, a2=a0, a3=a0;
    const float* wrow = sw1t + j*WID;
    #pragma unroll
    for(int c4=0;c4<WID;c4+=4){
      float4 w = *(const float4*)(wrow + c4);        // broadcast b128
      a0 += vv[     c4]*w.x + vv[     c4+1]*w.y + vv[     c4+2]*w.z + vv[     c4+3]*w.w;
      a1 += vv[32 + c4]*w.x + vv[32 + c4+1]*w.y + vv[32 + c4+2]*w.z + vv[32 + c4+3]*w.w;
      a2 += vv[64 + c4]*w.x + vv[64 + c4+1]*w.y + vv[64 + c4+2]*w.z + vv[64 + c4+3]*w.w;
      a3 += vv[96 + c4]*w.x + vv[96 + c4+1]*w.y + vv[96 + c4+2]*w.z + vv[96 + c4+3]*w.w;
    }
    a0=gelu_f(a0); a1=gelu_f(a1); a2=gelu_f(a2); a3=gelu_f(a3);
    float u0=sw2[2*j], u1=sw2[2*j+1];
    oa[0]+=a0*u0; oa[1]+=a0*u1; oa[2]+=a1*u0; oa[3]+=a1*u1;
    oa[4]+=a2*u0; oa[5]+=a2*u1; oa[6]+=a3*u0; oa[7]+=a3*u1;
  }
  float4* op = (float4*)(out + p0*2);
  op[0]=make_float4(oa[0],oa[1],oa[2],oa[3]);
  op[1]=make_float4(oa[4],oa[5],oa[6],oa[7]);
}

extern "C" void kernel_launch(void* const* d_in, const int* in_sizes, int n_in,
                              void* d_out, int out_size, void* d_ws, size_t ws_size,
                              hipStream_t stream){
  const float* h     = (const float*)d_in[0];
  const float* x     = (const float*)d_in[1];
  const float* fc0_w = (const float*)d_in[2];
  const float* fc0_b = (const float*)d_in[3];
  const float* scwr[3] = {(const float*)d_in[4], (const float*)d_in[6], (const float*)d_in[8]};
  const float* scwi[3] = {(const float*)d_in[5], (const float*)d_in[7], (const float*)d_in[9]};
  const float* cw[3]   = {(const float*)d_in[10], (const float*)d_in[12], (const float*)d_in[14]};
  const float* cb[3]   = {(const float*)d_in[11], (const float*)d_in[13], (const float*)d_in[15]};
  const float* fc1_w = (const float*)d_in[16];
  const float* fc1_b = (const float*)d_in[17];
  const float* fc2_w = (const float*)d_in[18];
  const float* fc2_b = (const float*)d_in[19];

  // workspace: V (167.8 MB, layout [b,x,y,t,c]) | F2 (25.2 MB) | F4 (9.4 MB)
  // F3 lives in d_out (9.4 MB <= 10.5 MB) until k_mlp overwrites it.
  const size_t VSZ = (size_t)BATCH*WID*NXYT;
  float*  V  = (float*)d_ws;
  float2* F2 = (float2*)(V + VSZ);
  float2* F4 = F2 + (size_t)BATCH*WID*NX*KYC*KT;
  float2* F3 = (float2*)d_out;

  k_fc0<<<NP/32, 256, 0, stream>>>(h, x, fc0_w, fc0_b, V);
  for(int L=0; L<3; L++){
    k_fwd_ty<<<BATCH*NX, 256, 0, stream>>>(V, F2);
    k_fwd_x<<<(BATCH*WID)*KYC, 256, 0, stream>>>(F2, F3);
    k_mix<<<KXC*KYC, 256, 0, stream>>>(F3, scwr[L], scwi[L], F4);
    k_inv_x<<<(BATCH*WID)*KYC, 256, 0, stream>>>(F4, F2);
    if(L<2) k_conv<true ><<<BATCH*NX*2, 256, 0, stream>>>(F2, cw[L], cb[L], V);
    else    k_conv<false><<<BATCH*NX*2, 256, 0, stream>>>(F2, cw[L], cb[L], V);
  }
  k_mlp<<<NP/1024, 256, 0, stream>>>(V, fc1_w, fc1_b, fc2_w, fc2_b, (float*)d_out);
}